// Round 13
// baseline (249.740 us; speedup 1.0000x reference)
//
#include <hip/hip_runtime.h>
#include <math.h>

// Problem constants
#define Bn 2
#define Sn 512
#define Hn 128
#define NHn 4
#define Dn 32
#define BAGn 5
#define NMETAn 16
#define ROWS 1024
#define NBn 2
#define Tt 257

#define NEGF (-4294967295.0f)
#define INV_SQRT_D 0.17677669529663687f
#define SQRT_H 11.313708498984761f
#define EPS_EMB 1e-5f
#define EPSF 1e-8f

// workspace float offsets
#define OFF_QN    0
#define OFF_Q     131072
#define OFF_K     262144
#define OFF_V     393216
#define OFF_O     524288

static __device__ __forceinline__ float red64(float v) {
#pragma unroll
    for (int m = 1; m < 64; m <<= 1) v += __shfl_xor(v, m, 64);
    return v;
}
static __device__ __forceinline__ float red64max(float v) {
#pragma unroll
    for (int m = 1; m < 64; m <<= 1) v = fmaxf(v, __shfl_xor(v, m, 64));
    return v;
}
static __device__ __forceinline__ float dot4(float4 a, float4 b) {
    return a.x * b.x + a.y * b.y + a.z * b.z + a.w * b.w;
}
static __device__ __forceinline__ float red4(float v) {
    v += __shfl_xor(v, 1, 64);
    v += __shfl_xor(v, 2, 64);
    return v;
}

// ===========================================================================
// Embed + embLN + keep + attnLN(0) + QKV(0). ROUND-9 VERBATIM (219.7 config).
// ===========================================================================
__global__ __launch_bounds__(256) void embed_qkv_kernel(
    const int* __restrict__ ids, const float* __restrict__ meta,
    const int* __restrict__ cats,
    const float* __restrict__ item_w, const float* __restrict__ cat_w,
    const float* __restrict__ numW, const float* __restrict__ numb,
    const float* __restrict__ fusW, const float* __restrict__ fusb,
    const float* __restrict__ elng, const float* __restrict__ elnb,
    const float* __restrict__ alng, const float* __restrict__ alnb,
    const float* __restrict__ QW, const float* __restrict__ Qb,
    const float* __restrict__ KW, const float* __restrict__ Kb,
    const float* __restrict__ VW, const float* __restrict__ Vb,
    const float* __restrict__ posK, const float* __restrict__ posV,
    const int* __restrict__ tmat, const float* __restrict__ tKw,
    const float* __restrict__ tVw,
    float* __restrict__ Qn, float* __restrict__ Q,
    float* __restrict__ K, float* __restrict__ V)
{
    int r0 = blockIdx.x * 2, t = threadIdx.x;
    __shared__ __align__(16) float combs[512];
    __shared__ __align__(16) float xs[256];
    __shared__ __align__(16) float qs[256];
    __shared__ float wsum[8];
    __shared__ int idl[2];

    // prefetch: re-warm L2/L3 after the harness's workspace poison sweep
    int pfi = 0; float pff = 0.f;
    {
        const int* tm = tmat + blockIdx.x * 1024;
#pragma unroll
        for (int j = 0; j < 4; ++j) pfi += tm[t + j * 256];
        if (t < 64) {
            int off = blockIdx.x * 64 + t;
            pff = tKw[off] + tVw[off];
        } else if (blockIdx.x == 0 && t < 192) {
            pff = tKw[32704 + t] + tVw[32704 + t];
        }
    }

    if (t < 2) idl[t] = ids[r0 + t];
    __syncthreads();
    { int r = t >> 7, c = t & 127; combs[r * 256 + c] = item_w[idl[r] * Hn + c] * SQRT_H; }
    if (t < 128) {
        int r = t >> 6, c = t & 63;
        const float4* m4 = (const float4*)(meta + (r0 + r) * NMETAn);
        const float4* w4 = (const float4*)(numW + c * NMETAn);
        float acc = numb[c];
#pragma unroll
        for (int j = 0; j < 4; ++j) acc += dot4(m4[j], w4[j]);
        combs[r * 256 + 128 + c] = acc;
    } else {
        int u = t - 128, r = u >> 6, c = u & 63;
        float ca = 0.f; int cnt = 0;
#pragma unroll
        for (int k2 = 0; k2 < BAGn; ++k2) {
            int cc2 = cats[(r0 + r) * BAGn + k2];
            if (cc2 != 0) { ca += cat_w[cc2 * 64 + c]; cnt++; }
        }
        combs[r * 256 + 192 + c] = ca / (float)(cnt > 0 ? cnt : 1);
    }
    asm volatile("" :: "v"(pfi), "v"(pff));
    __syncthreads();

    int q = t & 3, g = t >> 2;
#pragma unroll
    for (int p = 0; p < 2; ++p) {
        int h = p * 64 + g;
        const float4* w4 = (const float4*)(fusW + h * 256) + q;
        const float4* c0 = (const float4*)(combs) + q;
        const float4* c1 = (const float4*)(combs + 256) + q;
        float a0 = 0.f, a1 = 0.f;
#pragma unroll
        for (int j = 0; j < 16; ++j) {
            float4 w = w4[j * 4];
            a0 += dot4(c0[j * 4], w);
            a1 += dot4(c1[j * 4], w);
        }
        a0 = red4(a0); a1 = red4(a1);
        if (q == 0)      xs[h]       = a0 + fusb[h];
        else if (q == 1) xs[128 + h] = a1 + fusb[h];
    }
    __syncthreads();

    int w_ = t >> 6, row = w_ >> 1, l = t & 63, ch = ((w_ & 1) << 6) + l;
    float x = xs[row * 128 + ch];
    float s1 = red64(x);
    if (l == 0) wsum[w_] = s1;
    __syncthreads();
    float mean = (wsum[row * 2] + wsum[row * 2 + 1]) * (1.f / 128.f);
    float dlt = x - mean;
    float s2 = red64(dlt * dlt);
    if (l == 0) wsum[4 + w_] = s2;
    __syncthreads();
    float rstd = rsqrtf((wsum[4 + row * 2] + wsum[4 + row * 2 + 1]) * (1.f / 128.f) + EPS_EMB);
    float xv = dlt * rstd * elng[ch] + elnb[ch];
    xv = (idl[row] == 0) ? 0.f : xv;
    __syncthreads();
    xs[row * 128 + ch] = xv;
    __syncthreads();
    s1 = red64(xv);
    if (l == 0) wsum[w_] = s1;
    __syncthreads();
    mean = (wsum[row * 2] + wsum[row * 2 + 1]) * (1.f / 128.f);
    dlt = xv - mean;
    s2 = red64(dlt * dlt);
    if (l == 0) wsum[4 + w_] = s2;
    __syncthreads();
    rstd = rsqrtf((wsum[4 + row * 2] + wsum[4 + row * 2 + 1]) * (1.f / 128.f) + EPSF);
    float qn = dlt * rstd * alng[ch] + alnb[ch];
    qs[row * 128 + ch] = qn;
    Qn[(r0 + row) * 128 + ch] = qn;
    __syncthreads();

#pragma unroll
    for (int p = 0; p < 2; ++p) {
        int h = p * 64 + g;
        const float4* qw = (const float4*)(QW + h * 128) + q;
        const float4* kw = (const float4*)(KW + h * 128) + q;
        const float4* vw = (const float4*)(VW + h * 128) + q;
        const float4* s0p = (const float4*)(qs) + q;
        const float4* s1p = (const float4*)(qs + 128) + q;
        const float4* x0p = (const float4*)(xs) + q;
        const float4* x1p = (const float4*)(xs + 128) + q;
        float aq0 = 0, aq1 = 0, ak0 = 0, ak1 = 0, av0 = 0, av1 = 0;
#pragma unroll
        for (int j = 0; j < 8; ++j) {
            float4 wq = qw[j * 4], wk = kw[j * 4], wv = vw[j * 4];
            float4 u0 = s0p[j * 4], u1 = s1p[j * 4];
            float4 y0 = x0p[j * 4], y1 = x1p[j * 4];
            aq0 += dot4(u0, wq); aq1 += dot4(u1, wq);
            ak0 += dot4(y0, wk); ak1 += dot4(y1, wk);
            av0 += dot4(y0, wv); av1 += dot4(y1, wv);
        }
        aq0 = red4(aq0); aq1 = red4(aq1);
        ak0 = red4(ak0); ak1 = red4(ak1);
        av0 = red4(av0); av1 = red4(av1);
        if (q == 0) {
            int si = r0 & (Sn - 1);
            Q[r0 * Hn + h] = aq0 + Qb[h];
            K[r0 * Hn + h] = ak0 + Kb[h] + posK[si * Hn + h];
            V[r0 * Hn + h] = av0 + Vb[h] + posV[si * Hn + h];
        } else if (q == 1) {
            int si = (r0 + 1) & (Sn - 1);
            Q[(r0 + 1) * Hn + h] = aq1 + Qb[h];
            K[(r0 + 1) * Hn + h] = ak1 + Kb[h] + posK[si * Hn + h];
            V[(r0 + 1) * Hn + h] = av1 + Vb[h] + posV[si * Hn + h];
        }
    }
}

// ===========================================================================
// Attention round 13: 8 QUERIES PER BLOCK (512 blocks), same 64-key tiles.
// Each staged K/V tile + each QT table now serves 8 queries instead of 4:
// total tile stagings and tKw/QT phases HALVE; score/PV per query is the
// round-9 proven path (each wave serves its 2 queries sequentially).
// LDS 29.3KB -> 2 blocks/CU under the calibrated ~64KB budget.
// __launch_bounds__(256,2): generous 256-VGPR budget so qa/qb (64 regs,
// live across barriers) don't trigger the round-11 spill heuristic.
// Balance: s=blk>>3, g = (s<32)? s : 95-s -> co-resident {g, 63-g},
// per-CU tile sum ~10 (constant).
// ===========================================================================
__global__ __launch_bounds__(256, 2) void attn_kernel(
    const int* ids, const int* tmat,
    const float* Q, const float* K, const float* V,
    const float* tKw, const float* tVw, float* O)
{
    __shared__ __align__(16) float Kt[64 * 36];
    __shared__ __align__(16) float Vt[64 * 36];
    __shared__ float Stile[4 * 64];
    __shared__ int   trowT[4 * 64];
    __shared__ float QTl[8 * 260];
    __shared__ __align__(16) float ql[8 * 36];
    __shared__ int tlf[8];

    int blk = blockIdx.x, t = threadIdx.x;
    int bh = blk & 7;
    int s  = blk >> 3;               // 0..63
    int g  = (s < 32) ? s : 95 - s;  // co-resident pair {g, 63-g}
    int b = bh >> 2, h = bh & 3;
    int i0 = g * 8;

    if (t < 8) tlf[t] = (ids[b * Sn + i0 + t] == 0) ? 1 : 0;
    { int q_ = t >> 5, d = t & 31;
      ql[q_ * 36 + d] = Q[(b * Sn + i0 + q_) * Hn + h * 32 + d]; }
    __syncthreads();

    // fused QT for 8 queries, coalesced k-split (16 rows/line-touch per instr)
    {
        int qq = t & 3, gg = t >> 2;
#pragma unroll
        for (int c = 0; c < 5; ++c) {
            int tt = c * 64 + gg;
            if (tt < Tt) {
                const float4* tk4 = (const float4*)(tKw + tt * Hn + h * 32);
                float4 wA = tk4[qq];
                float4 wB = tk4[qq + 4];
                int dA = qq * 4, dB = 16 + qq * 4;
#pragma unroll
                for (int qi = 0; qi < 8; ++qi) {
                    const float* r_ = ql + qi * 36;
                    float a = r_[dA]*wA.x + r_[dA+1]*wA.y + r_[dA+2]*wA.z + r_[dA+3]*wA.w
                            + r_[dB]*wB.x + r_[dB+1]*wB.y + r_[dB+2]*wB.z + r_[dB+3]*wB.w;
                    a = red4(a);
                    if (qq == (qi & 3)) QTl[qi * 260 + tt] = a;  // lane qq owns qi, qi+4
                }
            }
        }
    }

    int tl_any = 0;
#pragma unroll
    for (int i = 0; i < 8; ++i) tl_any |= tlf[i];
    int ntiles = tl_any ? 8 : ((i0 + 7) >> 6) + 1;

    int w = t >> 6, jj = t & 63;
    int q0 = w * 2;                  // this wave's two queries
    int i_g0 = i0 + q0, i_g1 = i0 + q0 + 1;
    int tl0 = tlf[q0], tl1 = tlf[q0 + 1];
    const int* trow0 = tmat + (size_t)(b * Sn + i_g0) * Sn;
    const int* trow1 = tmat + (size_t)(b * Sn + i_g1) * Sn;

    float4 qa[8], qb[8];
    {
        const float4* p0 = (const float4*)(ql + q0 * 36);
        const float4* p1 = (const float4*)(ql + (q0 + 1) * 36);
#pragma unroll
        for (int d = 0; d < 8; ++d) { qa[d] = p0[d]; qb[d] = p1[d]; }
    }

    int jq = jj >> 5, d = jj & 31;
    float m0 = -INFINITY, l0 = 0.f, a0 = 0.f;
    float m1 = -INFINITY, l1 = 0.f, a1 = 0.f;

    for (int jt = 0; jt < ntiles; ++jt) {
        int j0 = jt * 64;
        __syncthreads();           // prior tile's reads done before re-staging
        for (int f = t; f < 512; f += 256) {
            int jl = f >> 3, dv = f & 7;
            float4 w4 = *(const float4*)(K + (size_t)(b * Sn + j0 + jl) * Hn + h * 32 + dv * 4);
            *(float4*)(Kt + jl * 36 + dv * 4) = w4;
            float4 v4 = *(const float4*)(V + (size_t)(b * Sn + j0 + jl) * Hn + h * 32 + dv * 4);
            *(float4*)(Vt + jl * 36 + dv * 4) = v4;
        }
        __syncthreads();

        // ---- query q0 (round-9 per-query path) ----
        if (tl0 || j0 <= i_g0) {
            int j = j0 + jj;
            float sv = NEGF;
            int tv = trow0[j];
            if (!tl0 && j <= i_g0) {
                const float4* kr = (const float4*)(Kt + jj * 36);
                float a = 0.f;
#pragma unroll
                for (int dd = 0; dd < 8; ++dd) a += dot4(qa[dd], kr[dd]);
                sv = (a + QTl[q0 * 260 + tv]) * INV_SQRT_D;
            }
            float mt = red64max(sv);
            float mnew = fmaxf(m0, mt);
            float alpha = expf(m0 - mnew);
            float p = expf(sv - mnew);
            l0 = l0 * alpha + red64(p);
            m0 = mnew;
            a0 *= alpha;
            Stile[w * 64 + jj] = p;
            trowT[w * 64 + jj] = tv;
            int base = jq * 32;
#pragma unroll 8
            for (int jl = base; jl < base + 32; ++jl) {
                float pp = Stile[w * 64 + jl];
                int tv2 = trowT[w * 64 + jl];
                a0 += pp * (Vt[jl * 36 + d] + tVw[tv2 * Hn + h * 32 + d]);
            }
        }
        // ---- query q0+1 (same-wave Stile/trowT reuse; in-order DS) ----
        if (tl1 || j0 <= i_g1) {
            int j = j0 + jj;
            float sv = NEGF;
            int tv = trow1[j];
            if (!tl1 && j <= i_g1) {
                const float4* kr = (const float4*)(Kt + jj * 36);
                float a = 0.f;
#pragma unroll
                for (int dd = 0; dd < 8; ++dd) a += dot4(qb[dd], kr[dd]);
                sv = (a + QTl[(q0 + 1) * 260 + tv]) * INV_SQRT_D;
            }
            float mt = red64max(sv);
            float mnew = fmaxf(m1, mt);
            float alpha = expf(m1 - mnew);
            float p = expf(sv - mnew);
            l1 = l1 * alpha + red64(p);
            m1 = mnew;
            a1 *= alpha;
            Stile[w * 64 + jj] = p;
            trowT[w * 64 + jj] = tv;
            int base = jq * 32;
#pragma unroll 8
            for (int jl = base; jl < base + 32; ++jl) {
                float pp = Stile[w * 64 + jl];
                int tv2 = trowT[w * 64 + jl];
                a1 += pp * (Vt[jl * 36 + d] + tVw[tv2 * Hn + h * 32 + d]);
            }
        }
    }

    float o0 = a0 + __shfl_xor(a0, 32, 64);
    float o1 = a1 + __shfl_xor(a1, 32, 64);
    if (jj < 32) {
        O[(size_t)(b * Sn + i_g0) * Hn + h * 32 + d] = o0 / l0;
        O[(size_t)(b * Sn + i_g1) * Hn + h * 32 + d] = o1 / l1;
    }
}

// ===========================================================================
// FFN(nb) -> [attnLN(nb+1)+QKV(nb+1)] or [final LN -> out]. ROUND-9 VERBATIM.
// ===========================================================================
__global__ __launch_bounds__(256) void ffn_qkv_kernel(
    const int* __restrict__ ids, float* __restrict__ Qn,
    const float* __restrict__ O,
    const float* __restrict__ flng, const float* __restrict__ flnb,
    const float* __restrict__ w1W, const float* __restrict__ w1b,
    const float* __restrict__ w2W, const float* __restrict__ w2b,
    const float* __restrict__ alng, const float* __restrict__ alnb,
    const float* __restrict__ QW, const float* __restrict__ Qb,
    const float* __restrict__ KW, const float* __restrict__ Kb,
    const float* __restrict__ VW, const float* __restrict__ Vb,
    const float* __restrict__ posK, const float* __restrict__ posV,
    float* __restrict__ Q, float* __restrict__ K, float* __restrict__ V,
    const float* __restrict__ llng, const float* __restrict__ llnb,
    float* __restrict__ out, int nb, int last)
{
    int r0 = blockIdx.x * 2, t = threadIdx.x;
    __shared__ __align__(16) float ys[256];
    __shared__ __align__(16) float h1s[256];
    __shared__ float wsum[8];
    int id0 = ids[r0], id1 = ids[r0 + 1];

    ys[t] = Qn[r0 * 128 + t] + O[r0 * 128 + t];
    __syncthreads();
    int w_ = t >> 6, row = w_ >> 1, l = t & 63, ch = ((w_ & 1) << 6) + l;
    float x = ys[row * 128 + ch];
    float s1 = red64(x);
    if (l == 0) wsum[w_] = s1;
    __syncthreads();
    float mean = (wsum[row * 2] + wsum[row * 2 + 1]) * (1.f / 128.f);
    float dlt = x - mean;
    float s2 = red64(dlt * dlt);
    if (l == 0) wsum[4 + w_] = s2;
    __syncthreads();
    float rstd = rsqrtf((wsum[4 + row * 2] + wsum[4 + row * 2 + 1]) * (1.f / 128.f) + EPSF);
    float yv = dlt * rstd * flng[nb * 128 + ch] + flnb[nb * 128 + ch];
    __syncthreads();
    ys[row * 128 + ch] = yv;
    __syncthreads();

    int q = t & 3, g = t >> 2;
#pragma unroll
    for (int p = 0; p < 2; ++p) {
        int h = p * 64 + g;
        const float4* w4 = (const float4*)(w1W + nb * 16384 + h * 128) + q;
        const float4* y0 = (const float4*)(ys) + q;
        const float4* y1 = (const float4*)(ys + 128) + q;
        float a0 = 0.f, a1 = 0.f;
#pragma unroll
        for (int j = 0; j < 8; ++j) {
            float4 w = w4[j * 4];
            a0 += dot4(y0[j * 4], w);
            a1 += dot4(y1[j * 4], w);
        }
        a0 = red4(a0); a1 = red4(a1);
        if (q == 0) {
            float v0 = a0 + w1b[nb * 128 + h];
            h1s[h] = 0.5f * v0 * (1.f + erff(v0 * 0.70710678118654752f));
        } else if (q == 1) {
            float v1 = a1 + w1b[nb * 128 + h];
            h1s[128 + h] = 0.5f * v1 * (1.f + erff(v1 * 0.70710678118654752f));
        }
    }
    __syncthreads();

    float z00, z01, z10, z11;
    {
        float zz[2][2];
#pragma unroll
        for (int p = 0; p < 2; ++p) {
            int h = p * 64 + g;
            const float4* w4 = (const float4*)(w2W + nb * 16384 + h * 128) + q;
            const float4* y0 = (const float4*)(h1s) + q;
            const float4* y1 = (const float4*)(h1s + 128) + q;
            float a0 = 0.f, a1 = 0.f;
#pragma unroll
            for (int j = 0; j < 8; ++j) {
                float4 w = w4[j * 4];
                a0 += dot4(y0[j * 4], w);
                a1 += dot4(y1[j * 4], w);
            }
            a0 = red4(a0); a1 = red4(a1);
            float b_ = w2b[nb * 128 + h];
            zz[p][0] = (id0 == 0) ? 0.f : (a0 + b_ + ys[h]);
            zz[p][1] = (id1 == 0) ? 0.f : (a1 + b_ + ys[128 + h]);
        }
        z00 = zz[0][0]; z10 = zz[1][0]; z01 = zz[0][1]; z11 = zz[1][1];
    }
    __syncthreads();
    if (q == 0)      { h1s[g] = z00;        h1s[64 + g] = z10; }
    else if (q == 1) { h1s[128 + g] = z01;  h1s[192 + g] = z11; }
    __syncthreads();

    if (last) {
        x = h1s[row * 128 + ch];
        s1 = red64(x);
        if (l == 0) wsum[w_] = s1;
        __syncthreads();
        mean = (wsum[row * 2] + wsum[row * 2 + 1]) * (1.f / 128.f);
        dlt = x - mean;
        s2 = red64(dlt * dlt);
        if (l == 0) wsum[4 + w_] = s2;
        __syncthreads();
        rstd = rsqrtf((wsum[4 + row * 2] + wsum[4 + row * 2 + 1]) * (1.f / 128.f) + EPSF);
        out[(r0 + row) * 128 + ch] = dlt * rstd * llng[ch] + llnb[ch];
        return;
    }

    int nq = nb + 1;
    x = h1s[row * 128 + ch];
    s1 = red64(x);
    if (l == 0) wsum[w_] = s1;
    __syncthreads();
    mean = (wsum[row * 2] + wsum[row * 2 + 1]) * (1.f / 128.f);
    dlt = x - mean;
    s2 = red64(dlt * dlt);
    if (l == 0) wsum[4 + w_] = s2;
    __syncthreads();
    rstd = rsqrtf((wsum[4 + row * 2] + wsum[4 + row * 2 + 1]) * (1.f / 128.f) + EPSF);
    float qn = dlt * rstd * alng[nq * 128 + ch] + alnb[nq * 128 + ch];
    __syncthreads();
    ys[row * 128 + ch] = qn;
    Qn[(r0 + row) * 128 + ch] = qn;
    __syncthreads();

#pragma unroll
    for (int p = 0; p < 2; ++p) {
        int h = p * 64 + g;
        const float4* qw = (const float4*)(QW + nq * 16384 + h * 128) + q;
        const float4* kw = (const float4*)(KW + nq * 16384 + h * 128) + q;
        const float4* vw = (const float4*)(VW + nq * 16384 + h * 128) + q;
        const float4* s0p = (const float4*)(ys) + q;
        const float4* s1p = (const float4*)(ys + 128) + q;
        const float4* x0p = (const float4*)(h1s) + q;
        const float4* x1p = (const float4*)(h1s + 128) + q;
        float aq0 = 0, aq1 = 0, ak0 = 0, ak1 = 0, av0 = 0, av1 = 0;
#pragma unroll
        for (int j = 0; j < 8; ++j) {
            float4 wq = qw[j * 4], wk = kw[j * 4], wv = vw[j * 4];
            float4 u0 = s0p[j * 4], u1 = s1p[j * 4];
            float4 y0 = x0p[j * 4], y1 = x1p[j * 4];
            aq0 += dot4(u0, wq); aq1 += dot4(u1, wq);
            ak0 += dot4(y0, wk); ak1 += dot4(y1, wk);
            av0 += dot4(y0, wv); av1 += dot4(y1, wv);
        }
        aq0 = red4(aq0); aq1 = red4(aq1);
        ak0 = red4(ak0); ak1 = red4(ak1);
        av0 = red4(av0); av1 = red4(av1);
        if (q == 0) {
            int si = r0 & (Sn - 1);
            Q[r0 * Hn + h] = aq0 + Qb[nq * 128 + h];
            K[r0 * Hn + h] = ak0 + Kb[nq * 128 + h] + posK[si * Hn + h];
            V[r0 * Hn + h] = av0 + Vb[nq * 128 + h] + posV[si * Hn + h];
        } else if (q == 1) {
            int si = (r0 + 1) & (Sn - 1);
            Q[(r0 + 1) * Hn + h] = aq1 + Qb[nq * 128 + h];
            K[(r0 + 1) * Hn + h] = ak1 + Kb[nq * 128 + h] + posK[si * Hn + h];
            V[(r0 + 1) * Hn + h] = av1 + Vb[nq * 128 + h] + posV[si * Hn + h];
        }
    }
}

// ---------------------------------------------------------------------------
extern "C" void kernel_launch(void* const* d_in, const int* in_sizes, int n_in,
                              void* d_out, int out_size, void* d_ws, size_t ws_size,
                              hipStream_t stream) {
    const int*   ids   = (const int*)  d_in[0];
    const float* meta  = (const float*)d_in[1];
    const int*   cats  = (const int*)  d_in[2];
    const int*   tmat  = (const int*)  d_in[3];
    const float* itemw = (const float*)d_in[4];
    const float* catw  = (const float*)d_in[5];
    const float* numW  = (const float*)d_in[6];
    const float* numb  = (const float*)d_in[7];
    const float* fusW  = (const float*)d_in[8];
    const float* fusb  = (const float*)d_in[9];
    const float* elng  = (const float*)d_in[10];
    const float* elnb  = (const float*)d_in[11];
    const float* posK  = (const float*)d_in[12];
    const float* posV  = (const float*)d_in[13];
    const float* tKw   = (const float*)d_in[14];
    const float* tVw   = (const float*)d_in[15];
    const float* alng  = (const float*)d_in[16];
    const float* alnb  = (const float*)d_in[17];
    const float* QW    = (const float*)d_in[18];
    const float* Qb    = (const float*)d_in[19];
    const float* KW    = (const float*)d_in[20];
    const float* Kb    = (const float*)d_in[21];
    const float* VW    = (const float*)d_in[22];
    const float* Vb    = (const float*)d_in[23];
    const float* flng  = (const float*)d_in[24];
    const float* flnb  = (const float*)d_in[25];
    const float* w1W   = (const float*)d_in[26];
    const float* w1b   = (const float*)d_in[27];
    const float* w2W   = (const float*)d_in[28];
    const float* w2b   = (const float*)d_in[29];
    const float* llng  = (const float*)d_in[30];
    const float* llnb  = (const float*)d_in[31];
    (void)in_sizes; (void)n_in; (void)out_size; (void)ws_size;

    float* ws = (float*)d_ws;
    float* Qnp = ws + OFF_QN;
    float* Qp  = ws + OFF_Q;
    float* Kp  = ws + OFF_K;
    float* Vp  = ws + OFF_V;
    float* Op  = ws + OFF_O;
    float* outp = (float*)d_out;

    embed_qkv_kernel<<<ROWS / 2, 256, 0, stream>>>(
        ids, meta, cats, itemw, catw, numW, numb, fusW, fusb, elng, elnb,
        alng, alnb, QW, Qb, KW, Kb, VW, Vb, posK, posV, tmat, tKw, tVw,
        Qnp, Qp, Kp, Vp);
    for (int nb = 0; nb < NBn; ++nb) {
        attn_kernel<<<512, 256, 0, stream>>>(ids, tmat, Qp, Kp, Vp, tKw, tVw, Op);
        ffn_qkv_kernel<<<ROWS / 2, 256, 0, stream>>>(
            ids, Qnp, Op, flng, flnb, w1W, w1b, w2W, w2b,
            alng, alnb, QW, Qb, KW, Kb, VW, Vb, posK, posV,
            Qp, Kp, Vp, llng, llnb, outp, nb, (nb == NBn - 1) ? 1 : 0);
    }
}

// Round 14
// 221.091 us; speedup vs baseline: 1.1296x; 1.1296x over previous
//
#include <hip/hip_runtime.h>
#include <math.h>

// Problem constants
#define Bn 2
#define Sn 512
#define Hn 128
#define NHn 4
#define Dn 32
#define BAGn 5
#define NMETAn 16
#define ROWS 1024
#define NBn 2
#define Tt 257

#define NEGF (-4294967295.0f)
#define INV_SQRT_D 0.17677669529663687f
#define SQRT_H 11.313708498984761f
#define EPS_EMB 1e-5f
#define EPSF 1e-8f

// workspace float offsets
#define OFF_QN    0
#define OFF_Q     131072
#define OFF_K     262144
#define OFF_V     393216
#define OFF_O     524288

static __device__ __forceinline__ float red64(float v) {
#pragma unroll
    for (int m = 1; m < 64; m <<= 1) v += __shfl_xor(v, m, 64);
    return v;
}
static __device__ __forceinline__ float red64max(float v) {
#pragma unroll
    for (int m = 1; m < 64; m <<= 1) v = fmaxf(v, __shfl_xor(v, m, 64));
    return v;
}
static __device__ __forceinline__ float dot4(float4 a, float4 b) {
    return a.x * b.x + a.y * b.y + a.z * b.z + a.w * b.w;
}
// combine partial dot across the 4-lane k-split group (all 4 lanes get sum)
static __device__ __forceinline__ float red4(float v) {
    v += __shfl_xor(v, 1, 64);
    v += __shfl_xor(v, 2, 64);
    return v;
}

// ===========================================================================
// Embed + embLN + keep + attnLN(0) + QKV(0). 2 rows/block, 512 blocks.
// Coalesced k-split GEMVs (round 7) + tmat/tKw/tVw L2-rewarm prefetch (r8).
// ===========================================================================
__global__ __launch_bounds__(256) void embed_qkv_kernel(
    const int* __restrict__ ids, const float* __restrict__ meta,
    const int* __restrict__ cats,
    const float* __restrict__ item_w, const float* __restrict__ cat_w,
    const float* __restrict__ numW, const float* __restrict__ numb,
    const float* __restrict__ fusW, const float* __restrict__ fusb,
    const float* __restrict__ elng, const float* __restrict__ elnb,
    const float* __restrict__ alng, const float* __restrict__ alnb,
    const float* __restrict__ QW, const float* __restrict__ Qb,
    const float* __restrict__ KW, const float* __restrict__ Kb,
    const float* __restrict__ VW, const float* __restrict__ Vb,
    const float* __restrict__ posK, const float* __restrict__ posV,
    const int* __restrict__ tmat, const float* __restrict__ tKw,
    const float* __restrict__ tVw,
    float* __restrict__ Qn, float* __restrict__ Q,
    float* __restrict__ K, float* __restrict__ V)
{
    int r0 = blockIdx.x * 2, t = threadIdx.x;
    __shared__ __align__(16) float combs[512];
    __shared__ __align__(16) float xs[256];
    __shared__ __align__(16) float qs[256];
    __shared__ float wsum[8];
    __shared__ int idl[2];

    // ---- prefetch (issue early; consumed by asm below, never stored) ----
    int pfi = 0; float pff = 0.f;
    {
        const int* tm = tmat + blockIdx.x * 1024;      // 2MB / 512 blocks
#pragma unroll
        for (int j = 0; j < 4; ++j) pfi += tm[t + j * 256];
        if (t < 64) {
            int off = blockIdx.x * 64 + t;             // 32768 of 32896
            pff = tKw[off] + tVw[off];
        } else if (blockIdx.x == 0 && t < 192) {       // tail rows
            pff = tKw[32704 + t] + tVw[32704 + t];     // 32768..32895
        }
    }

    if (t < 2) idl[t] = ids[r0 + t];
    __syncthreads();
    { int r = t >> 7, c = t & 127; combs[r * 256 + c] = item_w[idl[r] * Hn + c] * SQRT_H; }
    if (t < 128) {
        int r = t >> 6, c = t & 63;
        const float4* m4 = (const float4*)(meta + (r0 + r) * NMETAn);
        const float4* w4 = (const float4*)(numW + c * NMETAn);
        float acc = numb[c];
#pragma unroll
        for (int j = 0; j < 4; ++j) acc += dot4(m4[j], w4[j]);
        combs[r * 256 + 128 + c] = acc;
    } else {
        int u = t - 128, r = u >> 6, c = u & 63;
        float ca = 0.f; int cnt = 0;
#pragma unroll
        for (int k2 = 0; k2 < BAGn; ++k2) {
            int cc2 = cats[(r0 + r) * BAGn + k2];
            if (cc2 != 0) { ca += cat_w[cc2 * 64 + c]; cnt++; }
        }
        combs[r * 256 + 192 + c] = ca / (float)(cnt > 0 ? cnt : 1);
    }
    asm volatile("" :: "v"(pfi), "v"(pff));   // keep prefetch loads live
    __syncthreads();

    int q = t & 3, g = t >> 2;
    // fusion GEMV (K=256), coalesced k-split, both rows share weight loads
#pragma unroll
    for (int p = 0; p < 2; ++p) {
        int h = p * 64 + g;
        const float4* w4 = (const float4*)(fusW + h * 256) + q;
        const float4* c0 = (const float4*)(combs) + q;
        const float4* c1 = (const float4*)(combs + 256) + q;
        float a0 = 0.f, a1 = 0.f;
#pragma unroll
        for (int j = 0; j < 16; ++j) {
            float4 w = w4[j * 4];
            a0 += dot4(c0[j * 4], w);
            a1 += dot4(c1[j * 4], w);
        }
        a0 = red4(a0); a1 = red4(a1);
        if (q == 0)      xs[h]       = a0 + fusb[h];
        else if (q == 1) xs[128 + h] = a1 + fusb[h];
    }
    __syncthreads();

    // embLN + keep + attnLN(0)
    int w_ = t >> 6, row = w_ >> 1, l = t & 63, ch = ((w_ & 1) << 6) + l;
    float x = xs[row * 128 + ch];
    float s1 = red64(x);
    if (l == 0) wsum[w_] = s1;
    __syncthreads();
    float mean = (wsum[row * 2] + wsum[row * 2 + 1]) * (1.f / 128.f);
    float dlt = x - mean;
    float s2 = red64(dlt * dlt);
    if (l == 0) wsum[4 + w_] = s2;
    __syncthreads();
    float rstd = rsqrtf((wsum[4 + row * 2] + wsum[4 + row * 2 + 1]) * (1.f / 128.f) + EPS_EMB);
    float xv = dlt * rstd * elng[ch] + elnb[ch];
    xv = (idl[row] == 0) ? 0.f : xv;
    __syncthreads();
    xs[row * 128 + ch] = xv;
    __syncthreads();
    s1 = red64(xv);
    if (l == 0) wsum[w_] = s1;
    __syncthreads();
    mean = (wsum[row * 2] + wsum[row * 2 + 1]) * (1.f / 128.f);
    dlt = xv - mean;
    s2 = red64(dlt * dlt);
    if (l == 0) wsum[4 + w_] = s2;
    __syncthreads();
    rstd = rsqrtf((wsum[4 + row * 2] + wsum[4 + row * 2 + 1]) * (1.f / 128.f) + EPSF);
    float qn = dlt * rstd * alng[ch] + alnb[ch];
    qs[row * 128 + ch] = qn;
    Qn[(r0 + row) * 128 + ch] = qn;
    __syncthreads();

    // QKV (K=128), coalesced k-split
#pragma unroll
    for (int p = 0; p < 2; ++p) {
        int h = p * 64 + g;
        const float4* qw = (const float4*)(QW + h * 128) + q;
        const float4* kw = (const float4*)(KW + h * 128) + q;
        const float4* vw = (const float4*)(VW + h * 128) + q;
        const float4* s0p = (const float4*)(qs) + q;
        const float4* s1p = (const float4*)(qs + 128) + q;
        const float4* x0p = (const float4*)(xs) + q;
        const float4* x1p = (const float4*)(xs + 128) + q;
        float aq0 = 0, aq1 = 0, ak0 = 0, ak1 = 0, av0 = 0, av1 = 0;
#pragma unroll
        for (int j = 0; j < 8; ++j) {
            float4 wq = qw[j * 4], wk = kw[j * 4], wv = vw[j * 4];
            float4 u0 = s0p[j * 4], u1 = s1p[j * 4];
            float4 y0 = x0p[j * 4], y1 = x1p[j * 4];
            aq0 += dot4(u0, wq); aq1 += dot4(u1, wq);
            ak0 += dot4(y0, wk); ak1 += dot4(y1, wk);
            av0 += dot4(y0, wv); av1 += dot4(y1, wv);
        }
        aq0 = red4(aq0); aq1 = red4(aq1);
        ak0 = red4(ak0); ak1 = red4(ak1);
        av0 = red4(av0); av1 = red4(av1);
        if (q == 0) {
            int si = r0 & (Sn - 1);
            Q[r0 * Hn + h] = aq0 + Qb[h];
            K[r0 * Hn + h] = ak0 + Kb[h] + posK[si * Hn + h];
            V[r0 * Hn + h] = av0 + Vb[h] + posV[si * Hn + h];
        } else if (q == 1) {
            int si = (r0 + 1) & (Sn - 1);
            Q[(r0 + 1) * Hn + h] = aq1 + Qb[h];
            K[(r0 + 1) * Hn + h] = ak1 + Kb[h] + posK[si * Hn + h];
            V[(r0 + 1) * Hn + h] = av1 + Vb[h] + posV[si * Hn + h];
        }
    }
}

// ===========================================================================
// Attention round 9 (session best, 219.7us): (a) Kt/Vt/ql stride 36 floats
// (144B rows, 16B aligned): score-row reads are 8x ds_read_b128 (bank
// pattern (9*jj+k) mod 32, 9 odd -> bijective, conflict-free); staging
// writes are float4. (b) no mid-tile barrier: Stile/trowT are written and
// read by the SAME wave (wave iq owns [iq*64+*]) -- same-wave LDS RAW is
// ordered by lgkmcnt; 2 barriers/tile. (c) QT coalesced k-split (r8).
// Structural experiments that LOST vs this config: coop-fusion (R4),
// slim-LDS 4x-occupancy (R5), attn+ffn merge (R10), reg-prefetch (R11),
// 8-query blocks (R13).
// ===========================================================================
static __device__ __forceinline__ void attn_phase(
    int b, int h, int i0, int t,
    const int* __restrict__ ids, const int* __restrict__ tmat,
    const float* __restrict__ Q, const float* __restrict__ K,
    const float* __restrict__ V,
    const float* __restrict__ tKw, const float* __restrict__ tVw,
    float* __restrict__ O,
    float* Kt, float* Vt, float* Stile, int* trowT,
    float* QTl, float* ql, int* tlf)
{
    if (t < 4) tlf[t] = (ids[b * Sn + i0 + t] == 0) ? 1 : 0;
    if (t < 128) {
        int q_ = t >> 5, d = t & 31;
        ql[q_ * 36 + d] = Q[(b * Sn + i0 + q_) * Hn + h * 32 + d];
    }
    __syncthreads();

    // fused QT, coalesced k-split over 4-lane groups (ql stride 36)
    {
        int qq = t & 3, gg = t >> 2;
#pragma unroll
        for (int c = 0; c < 4; ++c) {
            int tt = c * 64 + gg;
            const float4* tk4 = (const float4*)(tKw + tt * Hn + h * 32);
            float4 wA = tk4[qq];
            float4 wB = tk4[qq + 4];
            int dA = qq * 4, dB = 16 + qq * 4;
            float a0 = ql[dA]*wA.x + ql[dA+1]*wA.y + ql[dA+2]*wA.z + ql[dA+3]*wA.w
                     + ql[dB]*wB.x + ql[dB+1]*wB.y + ql[dB+2]*wB.z + ql[dB+3]*wB.w;
            float a1 = ql[36+dA]*wA.x + ql[37+dA]*wA.y + ql[38+dA]*wA.z + ql[39+dA]*wA.w
                     + ql[36+dB]*wB.x + ql[37+dB]*wB.y + ql[38+dB]*wB.z + ql[39+dB]*wB.w;
            float a2 = ql[72+dA]*wA.x + ql[73+dA]*wA.y + ql[74+dA]*wA.z + ql[75+dA]*wA.w
                     + ql[72+dB]*wB.x + ql[73+dB]*wB.y + ql[74+dB]*wB.z + ql[75+dB]*wB.w;
            float a3 = ql[108+dA]*wA.x + ql[109+dA]*wA.y + ql[110+dA]*wA.z + ql[111+dA]*wA.w
                     + ql[108+dB]*wB.x + ql[109+dB]*wB.y + ql[110+dB]*wB.z + ql[111+dB]*wB.w;
            a0 = red4(a0); a1 = red4(a1); a2 = red4(a2); a3 = red4(a3);
            if (qq == 0)      QTl[tt] = a0;
            else if (qq == 1) QTl[260 + tt] = a1;
            else if (qq == 2) QTl[520 + tt] = a2;
            else              QTl[780 + tt] = a3;
        }
        if (t < 4) {                       // row 256 (one 4-lane group)
            const float4* tk4 = (const float4*)(tKw + 256 * Hn + h * 32);
            float4 wA = tk4[t];
            float4 wB = tk4[t + 4];
            int dA = t * 4, dB = 16 + t * 4;
            float a0 = ql[dA]*wA.x + ql[dA+1]*wA.y + ql[dA+2]*wA.z + ql[dA+3]*wA.w
                     + ql[dB]*wB.x + ql[dB+1]*wB.y + ql[dB+2]*wB.z + ql[dB+3]*wB.w;
            float a1 = ql[36+dA]*wA.x + ql[37+dA]*wA.y + ql[38+dA]*wA.z + ql[39+dA]*wA.w
                     + ql[36+dB]*wB.x + ql[37+dB]*wB.y + ql[38+dB]*wB.z + ql[39+dB]*wB.w;
            float a2 = ql[72+dA]*wA.x + ql[73+dA]*wA.y + ql[74+dA]*wA.z + ql[75+dA]*wA.w
                     + ql[72+dB]*wB.x + ql[73+dB]*wB.y + ql[74+dB]*wB.z + ql[75+dB]*wB.w;
            float a3 = ql[108+dA]*wA.x + ql[109+dA]*wA.y + ql[110+dA]*wA.z + ql[111+dA]*wA.w
                     + ql[108+dB]*wB.x + ql[109+dB]*wB.y + ql[110+dB]*wB.z + ql[111+dB]*wB.w;
            a0 = red4(a0); a1 = red4(a1); a2 = red4(a2); a3 = red4(a3);
            if (t == 0)      QTl[256] = a0;
            else if (t == 1) QTl[516] = a1;
            else if (t == 2) QTl[776] = a2;
            else             QTl[1036] = a3;
        }
    }

    int tl_any = tlf[0] | tlf[1] | tlf[2] | tlf[3];
    int ntiles = tl_any ? 8 : ((i0 + 3) >> 6) + 1;

    int iq = t >> 6, jj = t & 63;
    int i_g = i0 + iq;
    int my_tl = tlf[iq];
    const int* trow = tmat + (b * Sn + i_g) * Sn;

    float4 qv[8];
    {
        const float4* qp = (const float4*)(ql + iq * 36);
#pragma unroll
        for (int d = 0; d < 8; ++d) qv[d] = qp[d];
    }

    int jq = jj >> 5, d = jj & 31;
    float m = -INFINITY, lsum = 0.f, acc = 0.f;

    for (int jt = 0; jt < ntiles; ++jt) {
        int j0 = jt * 64;
        __syncthreads();           // prior PV done before re-staging
        for (int f = t; f < 64 * 8; f += 256) {
            int jl = f >> 3, dv = f & 7;
            float4 w4 = *(const float4*)(K + (b * Sn + j0 + jl) * Hn + h * 32 + dv * 4);
            *(float4*)(Kt + jl * 36 + dv * 4) = w4;
            float4 v4 = *(const float4*)(V + (b * Sn + j0 + jl) * Hn + h * 32 + dv * 4);
            *(float4*)(Vt + jl * 36 + dv * 4) = v4;
        }
        __syncthreads();

        int active = my_tl || (j0 <= i_g);   // wave-uniform
        if (active) {
            int j = j0 + jj;
            float sv = NEGF;
            int tv = trow[j];
            if (!my_tl && j <= i_g) {
                const float4* kr = (const float4*)(Kt + jj * 36);
                float a = 0.f;
#pragma unroll
                for (int dd = 0; dd < 8; ++dd)
                    a += dot4(qv[dd], kr[dd]);
                sv = (a + QTl[iq * 260 + tv]) * INV_SQRT_D;
            }
            float mt = red64max(sv);
            float mnew = fmaxf(m, mt);
            float alpha = expf(m - mnew);    // m=-inf first tile -> 0
            float p = expf(sv - mnew);
            lsum = lsum * alpha + red64(p);
            m = mnew;
            acc *= alpha;
            Stile[iq * 64 + jj] = p;
            trowT[iq * 64 + jj] = tv;
            // no barrier: Stile/trowT are same-wave private (lgkmcnt orders)
            int base = jq * 32;
#pragma unroll 8
            for (int jl = base; jl < base + 32; ++jl) {
                float pp = Stile[iq * 64 + jl];
                int tv2 = trowT[iq * 64 + jl];
                acc += pp * (Vt[jl * 36 + d] + tVw[tv2 * Hn + h * 32 + d]);
            }
        }
    }

    // finalize: sum the two jq halves, divide by l
    float a2 = acc + __shfl_xor(acc, 32, 64);
    if (jj < 32)
        O[(b * Sn + i_g) * Hn + h * 32 + d] = a2 / lsum;
}

__global__ __launch_bounds__(256) void attn_kernel(
    const int* ids, const int* tmat,
    const float* Q, const float* K, const float* V,
    const float* tKw, const float* tVw, float* O)
{
    __shared__ __align__(16) float Kt[64 * 36];
    __shared__ __align__(16) float Vt[64 * 36];
    __shared__ float Stile[4 * 64];
    __shared__ int   trowT[4 * 64];
    __shared__ float QTl[4 * 260];
    __shared__ __align__(16) float ql[4 * 36];
    __shared__ int tlf[4];
    int blk = blockIdx.x, t = threadIdx.x;
    int bh = blk & 7;
    int s  = blk >> 3;
    int g = s >> 5, r = s & 31;
    int mm;
    if      (g == 0) mm = r;
    else if (g == 1) mm = 127 - r;
    else if (g == 2) mm = 32 + r;
    else             mm = 95 - r;   // per-CU tile sum always 18
    int b = bh >> 2, h = bh & 3;
    attn_phase(b, h, mm * 4, t, ids, tmat, Q, K, V, tKw, tVw, O,
               Kt, Vt, Stile, trowT, QTl, ql, tlf);
}

// ===========================================================================
// FFN(nb) -> [attnLN(nb+1)+QKV(nb+1)] or [final LN -> out]. 2 rows/block,
// 512 blocks, all GEMVs with the coalesced 4-lane k-split.
// ===========================================================================
__global__ __launch_bounds__(256) void ffn_qkv_kernel(
    const int* __restrict__ ids, float* __restrict__ Qn,
    const float* __restrict__ O,
    const float* __restrict__ flng, const float* __restrict__ flnb,
    const float* __restrict__ w1W, const float* __restrict__ w1b,
    const float* __restrict__ w2W, const float* __restrict__ w2b,
    const float* __restrict__ alng, const float* __restrict__ alnb,
    const float* __restrict__ QW, const float* __restrict__ Qb,
    const float* __restrict__ KW, const float* __restrict__ Kb,
    const float* __restrict__ VW, const float* __restrict__ Vb,
    const float* __restrict__ posK, const float* __restrict__ posV,
    float* __restrict__ Q, float* __restrict__ K, float* __restrict__ V,
    const float* __restrict__ llng, const float* __restrict__ llnb,
    float* __restrict__ out, int nb, int last)
{
    int r0 = blockIdx.x * 2, t = threadIdx.x;
    __shared__ __align__(16) float ys[256];
    __shared__ __align__(16) float h1s[256];
    __shared__ float wsum[8];
    int id0 = ids[r0], id1 = ids[r0 + 1];

    ys[t] = Qn[r0 * 128 + t] + O[r0 * 128 + t];
    __syncthreads();
    int w_ = t >> 6, row = w_ >> 1, l = t & 63, ch = ((w_ & 1) << 6) + l;
    float x = ys[row * 128 + ch];
    float s1 = red64(x);
    if (l == 0) wsum[w_] = s1;
    __syncthreads();
    float mean = (wsum[row * 2] + wsum[row * 2 + 1]) * (1.f / 128.f);
    float dlt = x - mean;
    float s2 = red64(dlt * dlt);
    if (l == 0) wsum[4 + w_] = s2;
    __syncthreads();
    float rstd = rsqrtf((wsum[4 + row * 2] + wsum[4 + row * 2 + 1]) * (1.f / 128.f) + EPSF);
    float yv = dlt * rstd * flng[nb * 128 + ch] + flnb[nb * 128 + ch];
    __syncthreads();
    ys[row * 128 + ch] = yv;
    __syncthreads();

    int q = t & 3, g = t >> 2;
    // w1 + gelu (K=128), coalesced k-split
#pragma unroll
    for (int p = 0; p < 2; ++p) {
        int h = p * 64 + g;
        const float4* w4 = (const float4*)(w1W + nb * 16384 + h * 128) + q;
        const float4* y0 = (const float4*)(ys) + q;
        const float4* y1 = (const float4*)(ys + 128) + q;
        float a0 = 0.f, a1 = 0.f;
#pragma unroll
        for (int j = 0; j < 8; ++j) {
            float4 w = w4[j * 4];
            a0 += dot4(y0[j * 4], w);
            a1 += dot4(y1[j * 4], w);
        }
        a0 = red4(a0); a1 = red4(a1);
        if (q == 0) {
            float v0 = a0 + w1b[nb * 128 + h];
            h1s[h] = 0.5f * v0 * (1.f + erff(v0 * 0.70710678118654752f));
        } else if (q == 1) {
            float v1 = a1 + w1b[nb * 128 + h];
            h1s[128 + h] = 0.5f * v1 * (1.f + erff(v1 * 0.70710678118654752f));
        }
    }
    __syncthreads();

    // w2 + residual + keep: accumulate both passes in regs, barrier, write
    float z00, z01, z10, z11;
    {
        float zz[2][2];
#pragma unroll
        for (int p = 0; p < 2; ++p) {
            int h = p * 64 + g;
            const float4* w4 = (const float4*)(w2W + nb * 16384 + h * 128) + q;
            const float4* y0 = (const float4*)(h1s) + q;
            const float4* y1 = (const float4*)(h1s + 128) + q;
            float a0 = 0.f, a1 = 0.f;
#pragma unroll
            for (int j = 0; j < 8; ++j) {
                float4 w = w4[j * 4];
                a0 += dot4(y0[j * 4], w);
                a1 += dot4(y1[j * 4], w);
            }
            a0 = red4(a0); a1 = red4(a1);
            float b_ = w2b[nb * 128 + h];
            zz[p][0] = (id0 == 0) ? 0.f : (a0 + b_ + ys[h]);
            zz[p][1] = (id1 == 0) ? 0.f : (a1 + b_ + ys[128 + h]);
        }
        z00 = zz[0][0]; z10 = zz[1][0]; z01 = zz[0][1]; z11 = zz[1][1];
    }
    __syncthreads();               // all h1s reads done before overwrite
    if (q == 0)      { h1s[g] = z00;        h1s[64 + g] = z10; }
    else if (q == 1) { h1s[128 + g] = z01;  h1s[192 + g] = z11; }
    __syncthreads();

    if (last) {
        x = h1s[row * 128 + ch];
        s1 = red64(x);
        if (l == 0) wsum[w_] = s1;
        __syncthreads();
        mean = (wsum[row * 2] + wsum[row * 2 + 1]) * (1.f / 128.f);
        dlt = x - mean;
        s2 = red64(dlt * dlt);
        if (l == 0) wsum[4 + w_] = s2;
        __syncthreads();
        rstd = rsqrtf((wsum[4 + row * 2] + wsum[4 + row * 2 + 1]) * (1.f / 128.f) + EPSF);
        out[(r0 + row) * 128 + ch] = dlt * rstd * llng[ch] + llnb[ch];
        return;
    }

    int nq = nb + 1;
    x = h1s[row * 128 + ch];
    s1 = red64(x);
    if (l == 0) wsum[w_] = s1;
    __syncthreads();
    mean = (wsum[row * 2] + wsum[row * 2 + 1]) * (1.f / 128.f);
    dlt = x - mean;
    s2 = red64(dlt * dlt);
    if (l == 0) wsum[4 + w_] = s2;
    __syncthreads();
    rstd = rsqrtf((wsum[4 + row * 2] + wsum[4 + row * 2 + 1]) * (1.f / 128.f) + EPSF);
    float qn = dlt * rstd * alng[nq * 128 + ch] + alnb[nq * 128 + ch];
    __syncthreads();
    ys[row * 128 + ch] = qn;
    Qn[(r0 + row) * 128 + ch] = qn;
    __syncthreads();

    // QKV(nq), coalesced k-split: Q from ys(=qn), K/V from h1s(=z)
#pragma unroll
    for (int p = 0; p < 2; ++p) {
        int h = p * 64 + g;
        const float4* qw = (const float4*)(QW + nq * 16384 + h * 128) + q;
        const float4* kw = (const float4*)(KW + nq * 16384 + h * 128) + q;
        const float4* vw = (const float4*)(VW + nq * 16384 + h * 128) + q;
        const float4* s0p = (const float4*)(ys) + q;
        const float4* s1p = (const float4*)(ys + 128) + q;
        const float4* x0p = (const float4*)(h1s) + q;
        const float4* x1p = (const float4*)(h1s + 128) + q;
        float aq0 = 0, aq1 = 0, ak0 = 0, ak1 = 0, av0 = 0, av1 = 0;
#pragma unroll
        for (int j = 0; j < 8; ++j) {
            float4 wq = qw[j * 4], wk = kw[j * 4], wv = vw[j * 4];
            float4 u0 = s0p[j * 4], u1 = s1p[j * 4];
            float4 y0 = x0p[j * 4], y1 = x1p[j * 4];
            aq0 += dot4(u0, wq); aq1 += dot4(u1, wq);
            ak0 += dot4(y0, wk); ak1 += dot4(y1, wk);
            av0 += dot4(y0, wv); av1 += dot4(y1, wv);
        }
        aq0 = red4(aq0); aq1 = red4(aq1);
        ak0 = red4(ak0); ak1 = red4(ak1);
        av0 = red4(av0); av1 = red4(av1);
        if (q == 0) {
            int si = r0 & (Sn - 1);
            Q[r0 * Hn + h] = aq0 + Qb[nq * 128 + h];
            K[r0 * Hn + h] = ak0 + Kb[nq * 128 + h] + posK[si * Hn + h];
            V[r0 * Hn + h] = av0 + Vb[nq * 128 + h] + posV[si * Hn + h];
        } else if (q == 1) {
            int si = (r0 + 1) & (Sn - 1);
            Q[(r0 + 1) * Hn + h] = aq1 + Qb[nq * 128 + h];
            K[(r0 + 1) * Hn + h] = ak1 + Kb[nq * 128 + h] + posK[si * Hn + h];
            V[(r0 + 1) * Hn + h] = av1 + Vb[nq * 128 + h] + posV[si * Hn + h];
        }
    }
}

// ---------------------------------------------------------------------------
extern "C" void kernel_launch(void* const* d_in, const int* in_sizes, int n_in,
                              void* d_out, int out_size, void* d_ws, size_t ws_size,
                              hipStream_t stream) {
    const int*   ids   = (const int*)  d_in[0];
    const float* meta  = (const float*)d_in[1];
    const int*   cats  = (const int*)  d_in[2];
    const int*   tmat  = (const int*)  d_in[3];
    const float* itemw = (const float*)d_in[4];
    const float* catw  = (const float*)d_in[5];
    const float* numW  = (const float*)d_in[6];
    const float* numb  = (const float*)d_in[7];
    const float* fusW  = (const float*)d_in[8];
    const float* fusb  = (const float*)d_in[9];
    const float* elng  = (const float*)d_in[10];
    const float* elnb  = (const float*)d_in[11];
    const float* posK  = (const float*)d_in[12];
    const float* posV  = (const float*)d_in[13];
    const float* tKw   = (const float*)d_in[14];
    const float* tVw   = (const float*)d_in[15];
    const float* alng  = (const float*)d_in[16];
    const float* alnb  = (const float*)d_in[17];
    const float* QW    = (const float*)d_in[18];
    const float* Qb    = (const float*)d_in[19];
    const float* KW    = (const float*)d_in[20];
    const float* Kb    = (const float*)d_in[21];
    const float* VW    = (const float*)d_in[22];
    const float* Vb    = (const float*)d_in[23];
    const float* flng  = (const float*)d_in[24];
    const float* flnb  = (const float*)d_in[25];
    const float* w1W   = (const float*)d_in[26];
    const float* w1b   = (const float*)d_in[27];
    const float* w2W   = (const float*)d_in[28];
    const float* w2b   = (const float*)d_in[29];
    const float* llng  = (const float*)d_in[30];
    const float* llnb  = (const float*)d_in[31];
    (void)in_sizes; (void)n_in; (void)out_size; (void)ws_size;

    float* ws = (float*)d_ws;
    float* Qnp = ws + OFF_QN;
    float* Qp  = ws + OFF_Q;
    float* Kp  = ws + OFF_K;
    float* Vp  = ws + OFF_V;
    float* Op  = ws + OFF_O;
    float* outp = (float*)d_out;

    embed_qkv_kernel<<<ROWS / 2, 256, 0, stream>>>(
        ids, meta, cats, itemw, catw, numW, numb, fusW, fusb, elng, elnb,
        alng, alnb, QW, Qb, KW, Kb, VW, Vb, posK, posV, tmat, tKw, tVw,
        Qnp, Qp, Kp, Vp);
    for (int nb = 0; nb < NBn; ++nb) {
        attn_kernel<<<1024, 256, 0, stream>>>(ids, tmat, Qp, Kp, Vp, tKw, tVw, Op);
        ffn_qkv_kernel<<<ROWS / 2, 256, 0, stream>>>(
            ids, Qnp, Op, flng, flnb, w1W, w1b, w2W, w2b,
            alng, alnb, QW, Qb, KW, Kb, VW, Vb, posK, posV,
            Qp, Kp, Vp, llng, llnb, outp, nb, (nb == NBn - 1) ? 1 : 0);
    }
}